// Round 4
// baseline (405.221 us; speedup 1.0000x reference)
//
#include <hip/hip_runtime.h>
#include <hip/hip_bf16.h>
#include <math.h>

#define V 100000
#define H 256
#define B 512

// ---------------------------------------------------------------------------
// Kernel 1: GRU cell. One block per batch element, 256 threads (one per hidden
// unit j). gi is a column-gather of w_ih at input[b]; gh is per-thread dot
// products of w_hh rows {j, j+H, j+2H} against h_b staged in LDS.
// Writes h_new straight into the second output slot (d_out + B*V).
// ---------------------------------------------------------------------------
__global__ __launch_bounds__(256) void gru_cell_kernel(
    const int*   __restrict__ input,
    const float* __restrict__ hidden,
    const float* __restrict__ w_ih,
    const float* __restrict__ w_hh,
    const float* __restrict__ b_ih,
    const float* __restrict__ b_hh,
    float*       __restrict__ h_out)   // (B,H)
{
    const int b = blockIdx.x;
    const int j = threadIdx.x;   // 0..255

    __shared__ float hs[H];
    hs[j] = hidden[b * H + j];
    __syncthreads();

    const int idx = input[b];
    // gate layout [r; z; n]
    float gi_r = w_ih[ j          * V + idx] + b_ih[j];
    float gi_z = w_ih[(j +     H) * V + idx] + b_ih[j + H];
    float gi_n = w_ih[(j + 2 * H) * V + idx] + b_ih[j + 2 * H];

    const float4* wr = reinterpret_cast<const float4*>(&w_hh[ j          * H]);
    const float4* wz = reinterpret_cast<const float4*>(&w_hh[(j +     H) * H]);
    const float4* wn = reinterpret_cast<const float4*>(&w_hh[(j + 2 * H) * H]);
    const float4* h4 = reinterpret_cast<const float4*>(hs);

    float ar = 0.f, az = 0.f, an = 0.f;
    #pragma unroll 8
    for (int k = 0; k < H / 4; ++k) {
        const float4 hv = h4[k];      // uniform address -> LDS broadcast
        const float4 a  = wr[k];
        const float4 c  = wz[k];
        const float4 d  = wn[k];
        ar += a.x * hv.x + a.y * hv.y + a.z * hv.z + a.w * hv.w;
        az += c.x * hv.x + c.y * hv.y + c.z * hv.z + c.w * hv.w;
        an += d.x * hv.x + d.y * hv.y + d.z * hv.z + d.w * hv.w;
    }

    const float h_r = ar + b_hh[j];
    const float h_z = az + b_hh[j + H];
    const float h_n = an + b_hh[j + 2 * H];

    const float r = 1.f / (1.f + expf(-(gi_r + h_r)));
    const float z = 1.f / (1.f + expf(-(gi_z + h_z)));
    const float n = tanhf(gi_n + r * h_n);
    const float hprev = hs[j];

    h_out[b * H + j] = (1.f - z) * n + z * hprev;
}

// ---------------------------------------------------------------------------
// Kernel 2: logit = tanh(h_new @ w_out.T + b_out), all fp32.
// Tile: 128 batch x 128 vocab per block, 256 threads, 8x8 outputs per thread.
// LDS staging in K-chunks of 32, transposed to [k][{b,v}] with stride 132
// (132*4 bytes keeps float4 alignment; breaks the 32-way bank conflict of a
// stride-128 transpose write down to 4-way, and makes the compute-side
// float4 reads conflict-free).
// ---------------------------------------------------------------------------
#define BB  128
#define VVT 128
#define KK  32
#define LST 132   // LDS row stride in floats (multiple of 4 -> 16B alignment)

__global__ __launch_bounds__(256, 4) void out_gemm_kernel(
    const float* __restrict__ hnew,   // (B,H)
    const float* __restrict__ w_out,  // (V,H)
    const float* __restrict__ b_out,  // (V)
    float*       __restrict__ logit)  // (B,V)
{
    __shared__ float h_s[KK * LST];
    __shared__ float w_s[KK * LST];

    const int tid = threadIdx.x;
    const int tx  = tid & 15;          // vocab group: 16 groups of 8 v
    const int ty  = tid >> 4;          // batch group: 16 groups of 8 b
    const int v0  = blockIdx.x * VVT;
    const int b0  = blockIdx.y * BB;

    float acc[8][8];
    #pragma unroll
    for (int i = 0; i < 8; ++i)
        #pragma unroll
        for (int j = 0; j < 8; ++j) acc[i][j] = 0.f;

    for (int k0 = 0; k0 < H; k0 += KK) {
        __syncthreads();   // protect LDS reuse from previous chunk's readers

        // Stage h tile: h_s[k][b] = hnew[(b0+b)*H + k0+k]; 128x32 floats.
        // float4 loads along k (coalesced), 4 scalar transposed LDS writes.
        #pragma unroll
        for (int i = 0; i < 4; ++i) {
            const int idx4 = i * 256 + tid;
            const int k4   = (idx4 & 7) * 4;
            const int bl   = idx4 >> 3;
            const float4 hv =
                *reinterpret_cast<const float4*>(&hnew[(b0 + bl) * H + k0 + k4]);
            h_s[(k4 + 0) * LST + bl] = hv.x;
            h_s[(k4 + 1) * LST + bl] = hv.y;
            h_s[(k4 + 2) * LST + bl] = hv.z;
            h_s[(k4 + 3) * LST + bl] = hv.w;
        }
        // Stage w tile: w_s[k][v] = w_out[(v0+v)*H + k0+k]; 128x32 floats.
        #pragma unroll
        for (int i = 0; i < 4; ++i) {
            const int idx4 = i * 256 + tid;
            const int k4   = (idx4 & 7) * 4;
            const int vl   = idx4 >> 3;
            int vg = v0 + vl;
            if (vg >= V) vg = V - 1;           // clamp; masked at store time
            const float4 wv =
                *reinterpret_cast<const float4*>(&w_out[vg * H + k0 + k4]);
            w_s[(k4 + 0) * LST + vl] = wv.x;
            w_s[(k4 + 1) * LST + vl] = wv.y;
            w_s[(k4 + 2) * LST + vl] = wv.z;
            w_s[(k4 + 3) * LST + vl] = wv.w;
        }
        __syncthreads();

        #pragma unroll 4
        for (int k = 0; k < KK; ++k) {
            const float4 a0 = *reinterpret_cast<const float4*>(&h_s[k * LST + ty * 8]);
            const float4 a1 = *reinterpret_cast<const float4*>(&h_s[k * LST + ty * 8 + 4]);
            const float4 w0 = *reinterpret_cast<const float4*>(&w_s[k * LST + tx * 8]);
            const float4 w1 = *reinterpret_cast<const float4*>(&w_s[k * LST + tx * 8 + 4]);
            const float av[8] = {a0.x, a0.y, a0.z, a0.w, a1.x, a1.y, a1.z, a1.w};
            const float wv[8] = {w0.x, w0.y, w0.z, w0.w, w1.x, w1.y, w1.z, w1.w};
            #pragma unroll
            for (int i = 0; i < 8; ++i)
                #pragma unroll
                for (int j = 0; j < 8; ++j)
                    acc[i][j] += av[i] * wv[j];
        }
    }

    // Epilogue: add bias, tanh, store (mask the partial last vocab tile).
    const int vbase = v0 + tx * 8;
    float bo[8];
    #pragma unroll
    for (int j = 0; j < 8; ++j)
        bo[j] = (vbase + j < V) ? b_out[vbase + j] : 0.f;

    #pragma unroll
    for (int i = 0; i < 8; ++i) {
        const int row = b0 + ty * 8 + i;
        float* dst = logit + (size_t)row * V;
        #pragma unroll
        for (int j = 0; j < 8; ++j) {
            if (vbase + j < V)
                dst[vbase + j] = tanhf(acc[i][j] + bo[j]);
        }
    }
}

// ---------------------------------------------------------------------------
extern "C" void kernel_launch(void* const* d_in, const int* in_sizes, int n_in,
                              void* d_out, int out_size, void* d_ws, size_t ws_size,
                              hipStream_t stream) {
    const int*   input  = (const int*)  d_in[0];
    // d_in[1] = target (unused by forward)
    const float* hidden = (const float*)d_in[2];
    const float* w_ih   = (const float*)d_in[3];
    const float* w_hh   = (const float*)d_in[4];
    const float* b_ih   = (const float*)d_in[5];
    const float* b_hh   = (const float*)d_in[6];
    const float* w_out  = (const float*)d_in[7];
    const float* b_out  = (const float*)d_in[8];

    float* out   = (float*)d_out;
    float* logit = out;                      // first B*V floats
    float* h_new = out + (size_t)B * V;      // then L*B*H floats (L=1)

    gru_cell_kernel<<<B, 256, 0, stream>>>(input, hidden, w_ih, w_hh,
                                           b_ih, b_hh, h_new);

    dim3 grid2((V + VVT - 1) / VVT, B / BB);  // (782, 4)
    out_gemm_kernel<<<grid2, 256, 0, stream>>>(h_new, w_out, b_out, logit);
}

// Round 5
// 230.095 us; speedup vs baseline: 1.7611x; 1.7611x over previous
//
#include <hip/hip_runtime.h>
#include <hip/hip_bf16.h>
#include <math.h>

#define V 100000
#define H 256
#define B 512

typedef __bf16 bf16x8 __attribute__((ext_vector_type(8)));
typedef float  f32x4  __attribute__((ext_vector_type(4)));

__device__ __forceinline__ unsigned short f32_bf16_rne(float x) {
    unsigned u = __float_as_uint(x);
    u += 0x7FFFu + ((u >> 16) & 1u);            // round-to-nearest-even
    return (unsigned short)(u >> 16);
}
__device__ __forceinline__ float bf16u_f32(unsigned short h) {
    return __uint_as_float(((unsigned)h) << 16);
}

// ---------------------------------------------------------------------------
// Kernel 1: GRU cell (unchanged from passing round). One block per batch
// element; writes h_new into d_out + B*V.
// ---------------------------------------------------------------------------
__global__ __launch_bounds__(256) void gru_cell_kernel(
    const int*   __restrict__ input,
    const float* __restrict__ hidden,
    const float* __restrict__ w_ih,
    const float* __restrict__ w_hh,
    const float* __restrict__ b_ih,
    const float* __restrict__ b_hh,
    float*       __restrict__ h_out)
{
    const int b = blockIdx.x;
    const int j = threadIdx.x;

    __shared__ float hs[H];
    hs[j] = hidden[b * H + j];
    __syncthreads();

    const int idx = input[b];
    float gi_r = w_ih[ j          * V + idx] + b_ih[j];
    float gi_z = w_ih[(j +     H) * V + idx] + b_ih[j + H];
    float gi_n = w_ih[(j + 2 * H) * V + idx] + b_ih[j + 2 * H];

    const float4* wr = reinterpret_cast<const float4*>(&w_hh[ j          * H]);
    const float4* wz = reinterpret_cast<const float4*>(&w_hh[(j +     H) * H]);
    const float4* wn = reinterpret_cast<const float4*>(&w_hh[(j + 2 * H) * H]);
    const float4* h4 = reinterpret_cast<const float4*>(hs);

    float ar = 0.f, az = 0.f, an = 0.f;
    #pragma unroll 8
    for (int k = 0; k < H / 4; ++k) {
        const float4 hv = h4[k];
        const float4 a  = wr[k];
        const float4 c  = wz[k];
        const float4 d  = wn[k];
        ar += a.x * hv.x + a.y * hv.y + a.z * hv.z + a.w * hv.w;
        az += c.x * hv.x + c.y * hv.y + c.z * hv.z + c.w * hv.w;
        an += d.x * hv.x + d.y * hv.y + d.z * hv.z + d.w * hv.w;
    }

    const float h_r = ar + b_hh[j];
    const float h_z = az + b_hh[j + H];
    const float h_n = an + b_hh[j + 2 * H];

    const float r = 1.f / (1.f + expf(-(gi_r + h_r)));
    const float z = 1.f / (1.f + expf(-(gi_z + h_z)));
    const float n = tanhf(gi_n + r * h_n);
    const float hprev = hs[j];

    h_out[b * H + j] = (1.f - z) * n + z * hprev;
}

// ---------------------------------------------------------------------------
// Kernel 2: logit = tanh(h_new @ w_out.T + b_out) via split-bf16 MFMA.
// Each fp32 split into bf16 hi/lo; acc += Ah*Bh + Ah*Bl + Al*Bh (fp32 MFMA acc).
// Tile 64b x 128v, BK=64, 4 waves (2x2), per-wave 32x64 = 2x4 fragments.
// LDS XOR-swizzled (T2) to kill the 16-way stride-128B ds_read_b128 conflict.
// Reg-staged with prefetch: chunk t+1 global loads issued before MFMA of t.
// ---------------------------------------------------------------------------
#define BM  64
#define BN  128
#define BK  64
#define NVB 782   // ceil(V/BN)
#define NBB 8     // B/BM

__global__ __launch_bounds__(256) void out_gemm_mfma(
    const float* __restrict__ hnew,   // (B,H)
    const float* __restrict__ w_out,  // (V,H)
    const float* __restrict__ b_out,  // (V)
    float*       __restrict__ logit)  // (B,V)
{
    __shared__ unsigned short w_hi[BN * BK];   // 16 KB
    __shared__ unsigned short w_lo[BN * BK];   // 16 KB
    __shared__ unsigned short h_hi[BM * BK];   //  8 KB
    __shared__ unsigned short h_lo[BM * BK];   //  8 KB

    const int tid  = threadIdx.x;
    const int lane = tid & 63;
    const int wid  = tid >> 6;
    const int wm   = wid >> 1;      // batch half (0..1)
    const int wn   = wid & 1;       // vocab half (0..1)

    // XCD-chunked bijective swizzle; batch-fastest work order so the 8 blocks
    // sharing a w_out tile land on the same XCD consecutively.
    const int bid = blockIdx.x;                    // 0..6255
    const int wg  = (bid & 7) * NVB + (bid >> 3);
    const int bx  = wg & 7;                        // batch block
    const int by  = wg >> 3;                       // vocab block
    const int b0  = bx * BM;
    const int v0  = by * BN;

    float4 wreg[8];
    float4 hreg[4];

    auto load_chunk = [&](int k0) {
        #pragma unroll
        for (int i = 0; i < 8; ++i) {
            const int idx4 = i * 256 + tid;
            const int row  = idx4 >> 4;            // 0..127 vocab row
            const int k4   = (idx4 & 15) << 2;     // 0..60
            int vg = v0 + row; if (vg > V - 1) vg = V - 1;   // clamp; masked at store
            wreg[i] = *reinterpret_cast<const float4*>(&w_out[(size_t)vg * H + k0 + k4]);
        }
        #pragma unroll
        for (int i = 0; i < 4; ++i) {
            const int idx4 = i * 256 + tid;
            const int row  = idx4 >> 4;            // 0..63 batch row
            const int k4   = (idx4 & 15) << 2;
            hreg[i] = *reinterpret_cast<const float4*>(&hnew[(b0 + row) * H + k0 + k4]);
        }
    };

    auto store_chunk = [&]() {
        #pragma unroll
        for (int i = 0; i < 8; ++i) {
            const int idx4 = i * 256 + tid;
            const int row  = idx4 >> 4;
            const int k4   = (idx4 & 15) << 2;
            const int off  = row * (BK * 2) + ((k4 * 2) ^ ((row & 7) << 4));
            const float f[4] = {wreg[i].x, wreg[i].y, wreg[i].z, wreg[i].w};
            unsigned short hv[4], lv[4];
            #pragma unroll
            for (int j = 0; j < 4; ++j) {
                hv[j] = f32_bf16_rne(f[j]);
                lv[j] = f32_bf16_rne(f[j] - bf16u_f32(hv[j]));
            }
            *reinterpret_cast<ushort4*>(reinterpret_cast<char*>(w_hi) + off) =
                make_ushort4(hv[0], hv[1], hv[2], hv[3]);
            *reinterpret_cast<ushort4*>(reinterpret_cast<char*>(w_lo) + off) =
                make_ushort4(lv[0], lv[1], lv[2], lv[3]);
        }
        #pragma unroll
        for (int i = 0; i < 4; ++i) {
            const int idx4 = i * 256 + tid;
            const int row  = idx4 >> 4;
            const int k4   = (idx4 & 15) << 2;
            const int off  = row * (BK * 2) + ((k4 * 2) ^ ((row & 7) << 4));
            const float f[4] = {hreg[i].x, hreg[i].y, hreg[i].z, hreg[i].w};
            unsigned short hv[4], lv[4];
            #pragma unroll
            for (int j = 0; j < 4; ++j) {
                hv[j] = f32_bf16_rne(f[j]);
                lv[j] = f32_bf16_rne(f[j] - bf16u_f32(hv[j]));
            }
            *reinterpret_cast<ushort4*>(reinterpret_cast<char*>(h_hi) + off) =
                make_ushort4(hv[0], hv[1], hv[2], hv[3]);
            *reinterpret_cast<ushort4*>(reinterpret_cast<char*>(h_lo) + off) =
                make_ushort4(lv[0], lv[1], lv[2], lv[3]);
        }
    };

    f32x4 acc[2][4];
    #pragma unroll
    for (int i = 0; i < 2; ++i)
        #pragma unroll
        for (int n = 0; n < 4; ++n)
            acc[i][n] = f32x4{0.f, 0.f, 0.f, 0.f};

    auto compute = [&]() {
        #pragma unroll
        for (int ks = 0; ks < 2; ++ks) {
            const int kb = ks * 64 + (lane >> 4) * 16;   // k byte offset (16B aligned)
            bf16x8 ah[2], al[2];
            #pragma unroll
            for (int i = 0; i < 2; ++i) {
                const int row = wm * 32 + i * 16 + (lane & 15);
                const int off = row * (BK * 2) + (kb ^ ((row & 7) << 4));
                ah[i] = *reinterpret_cast<const bf16x8*>(
                            reinterpret_cast<const char*>(h_hi) + off);
                al[i] = *reinterpret_cast<const bf16x8*>(
                            reinterpret_cast<const char*>(h_lo) + off);
            }
            #pragma unroll
            for (int n = 0; n < 4; ++n) {
                const int row = wn * 64 + n * 16 + (lane & 15);
                const int off = row * (BK * 2) + (kb ^ ((row & 7) << 4));
                const bf16x8 bh = *reinterpret_cast<const bf16x8*>(
                            reinterpret_cast<const char*>(w_hi) + off);
                const bf16x8 bl = *reinterpret_cast<const bf16x8*>(
                            reinterpret_cast<const char*>(w_lo) + off);
                #pragma unroll
                for (int i = 0; i < 2; ++i) {
                    acc[i][n] = __builtin_amdgcn_mfma_f32_16x16x32_bf16(ah[i], bh, acc[i][n], 0, 0, 0);
                    acc[i][n] = __builtin_amdgcn_mfma_f32_16x16x32_bf16(ah[i], bl, acc[i][n], 0, 0, 0);
                    acc[i][n] = __builtin_amdgcn_mfma_f32_16x16x32_bf16(al[i], bh, acc[i][n], 0, 0, 0);
                }
            }
        }
    };

    // Pipeline: loads for chunk t+1 in flight while MFMA of chunk t runs.
    load_chunk(0);
    store_chunk();
    __syncthreads();
    for (int t = 0; t < 4; ++t) {
        if (t < 3) load_chunk((t + 1) * BK);
        compute();
        __syncthreads();
        if (t < 3) { store_chunk(); __syncthreads(); }
    }

    // Epilogue: bias + tanh + masked store.
    // C/D layout: col = lane&15, row = (lane>>4)*4 + reg.
    float bias[4];
    int   cols[4];
    #pragma unroll
    for (int n = 0; n < 4; ++n) {
        const int c = v0 + wn * 64 + n * 16 + (lane & 15);
        cols[n] = c;
        bias[n] = (c < V) ? b_out[c] : 0.f;
    }
    const int rbase = b0 + wm * 32 + (lane >> 4) * 4;
    #pragma unroll
    for (int i = 0; i < 2; ++i) {
        #pragma unroll
        for (int r = 0; r < 4; ++r) {
            const int row = rbase + i * 16 + r;
            float* dst = logit + (size_t)row * V;
            #pragma unroll
            for (int n = 0; n < 4; ++n) {
                if (cols[n] < V)
                    dst[cols[n]] = tanhf(acc[i][n][r] + bias[n]);
            }
        }
    }
}

// ---------------------------------------------------------------------------
extern "C" void kernel_launch(void* const* d_in, const int* in_sizes, int n_in,
                              void* d_out, int out_size, void* d_ws, size_t ws_size,
                              hipStream_t stream) {
    const int*   input  = (const int*)  d_in[0];
    // d_in[1] = target (unused by forward)
    const float* hidden = (const float*)d_in[2];
    const float* w_ih   = (const float*)d_in[3];
    const float* w_hh   = (const float*)d_in[4];
    const float* b_ih   = (const float*)d_in[5];
    const float* b_hh   = (const float*)d_in[6];
    const float* w_out  = (const float*)d_in[7];
    const float* b_out  = (const float*)d_in[8];

    float* out   = (float*)d_out;
    float* logit = out;                      // first B*V floats
    float* h_new = out + (size_t)B * V;      // then L*B*H floats (L=1)

    gru_cell_kernel<<<B, 256, 0, stream>>>(input, hidden, w_ih, w_hh,
                                           b_ih, b_hh, h_new);

    out_gemm_mfma<<<NVB * NBB, 256, 0, stream>>>(h_new, w_out, b_out, logit);
}